// Round 2
// baseline (1362.433 us; speedup 1.0000x reference)
//
#include <hip/hip_runtime.h>
#include <cstdint>
#include <cstddef>

#define BATCH 8
#define CDIM 128
#define SEQ 2304
#define NEXP 3
#define HHID 8192
#define NPAR 16384

typedef unsigned short u16;
typedef __attribute__((ext_vector_type(8))) __bf16 bf16x8;
typedef __attribute__((ext_vector_type(4))) float f32x4;

__device__ __forceinline__ unsigned short f2b(float f) {
    union { float f; unsigned int i; } v; v.f = f;
    unsigned int x = v.i;
    unsigned int r = (x + 0x7fffu + ((x >> 16) & 1u)) >> 16;
    return (unsigned short)r;
}
__device__ __forceinline__ float b2f(unsigned short u) {
    union { unsigned int i; float f; } v; v.i = ((unsigned int)u) << 16; return v.f;
}
__device__ __forceinline__ void ld4bf(const u16* p, float* w) {
    uint2 u = *(const uint2*)p;
    w[0] = b2f((unsigned short)(u.x & 0xffffu));
    w[1] = b2f((unsigned short)(u.x >> 16));
    w[2] = b2f((unsigned short)(u.y & 0xffffu));
    w[3] = b2f((unsigned short)(u.y >> 16));
}

// ---------------- transpose: feature fp32 [B][C][S] -> seq fp32 [B][S][C] ----
__global__ __launch_bounds__(256) void k_transpose(const float* __restrict__ feat,
                                                   float* __restrict__ seq) {
    __shared__ float lt[128][69];   // pad 69: read conflicts ~4-way, writes ok
    int b = blockIdx.x, s0 = blockIdx.y * 64, t = threadIdx.x;
    for (int p = 0; p < 8; ++p) {
        int idx = p * 256 + t;            // 0..2047
        int c = idx >> 4, k4 = (idx & 15) * 4;
        float4 u = *(const float4*)(feat + (size_t)b * CDIM * SEQ + (size_t)c * SEQ + s0 + k4);
        lt[c][k4 + 0] = u.x; lt[c][k4 + 1] = u.y;
        lt[c][k4 + 2] = u.z; lt[c][k4 + 3] = u.w;
    }
    __syncthreads();
    for (int p = 0; p < 8; ++p) {
        int w = p * 256 + t;
        int s = w >> 5, c4 = (w & 31) * 4;
        float4 o;
        o.x = lt[c4 + 0][s]; o.y = lt[c4 + 1][s];
        o.z = lt[c4 + 2][s]; o.w = lt[c4 + 3][s];
        *(float4*)(seq + ((size_t)b * SEQ + s0 + s) * CDIM + c4) = o;
    }
}

// ---------------- QKV projection: seq fp32 -> q,k bf16 [B][S][C]; vT bf16 [B][C][S]
__global__ __launch_bounds__(256) void k_qkv(const float* __restrict__ seq,
        const float* __restrict__ qw, const float* __restrict__ kw, const float* __restrict__ vw,
        const float* __restrict__ qb, const float* __restrict__ kb, const float* __restrict__ vb,
        u16* __restrict__ qB, u16* __restrict__ kB, u16* __restrict__ vT) {
    __shared__ float lseq[32][132];
    __shared__ u16 lwT[128][140];
    int b = blockIdx.x, s0 = blockIdx.y * 32, t = threadIdx.x;
    for (int p = 0; p < 4; ++p) {
        int idx = p * 256 + t;
        int r = idx >> 5, c4 = (idx & 31) * 4;
        *(float4*)(&lseq[r][c4]) = *(const float4*)(seq + ((size_t)b * SEQ + s0 + r) * CDIM + c4);
    }
    for (int mat = 0; mat < 3; ++mat) {
        const float* w = (mat == 0) ? qw : (mat == 1) ? kw : vw;
        __syncthreads();
        for (int p = 0; p < 8; ++p) {
            int idx = p * 256 + t;
            int i = idx >> 4, oc8 = (idx & 15) * 8;
            float4 u0 = *(const float4*)(w + i * CDIM + oc8);
            float4 u1 = *(const float4*)(w + i * CDIM + oc8 + 4);
            lwT[oc8 + 0][i] = f2b(u0.x); lwT[oc8 + 1][i] = f2b(u0.y);
            lwT[oc8 + 2][i] = f2b(u0.z); lwT[oc8 + 3][i] = f2b(u0.w);
            lwT[oc8 + 4][i] = f2b(u1.x); lwT[oc8 + 5][i] = f2b(u1.y);
            lwT[oc8 + 6][i] = f2b(u1.z); lwT[oc8 + 7][i] = f2b(u1.w);
        }
        __syncthreads();
        if (mat < 2) {
            int oc = t & 127, sg = t >> 7;
            const float* bias = (mat == 0) ? qb : kb;
            float acc[16];
            float bv = bias[oc];
            #pragma unroll
            for (int j = 0; j < 16; ++j) acc[j] = bv;
            for (int i = 0; i < CDIM; i += 4) {
                float wf[4]; ld4bf(&lwT[oc][i], wf);
                #pragma unroll
                for (int j = 0; j < 16; ++j) {
                    float4 sv = *(const float4*)(&lseq[sg * 16 + j][i]);
                    acc[j] += sv.x * wf[0] + sv.y * wf[1] + sv.z * wf[2] + sv.w * wf[3];
                }
            }
            u16* outp = (mat == 0) ? qB : kB;
            #pragma unroll
            for (int j = 0; j < 16; ++j)
                outp[((size_t)b * SEQ + s0 + sg * 16 + j) * CDIM + oc] = f2b(acc[j]);
        } else {
            int s = t & 31, og = t >> 5;
            float acc[16];
            #pragma unroll
            for (int j = 0; j < 16; ++j) acc[j] = vb[og * 16 + j];
            for (int i = 0; i < CDIM; i += 4) {
                float4 sv = *(const float4*)(&lseq[s][i]);
                #pragma unroll
                for (int j = 0; j < 16; ++j) {
                    float wf[4]; ld4bf(&lwT[og * 16 + j][i], wf);
                    acc[j] += sv.x * wf[0] + sv.y * wf[1] + sv.z * wf[2] + sv.w * wf[3];
                }
            }
            #pragma unroll
            for (int j = 0; j < 16; ++j) {
                int oc = og * 16 + j;
                vT[(size_t)b * CDIM * SEQ + (size_t)oc * SEQ + s0 + s] = f2b(acc[j]);
            }
        }
    }
}

// ---------------- flash attention (MFMA bf16), seq += softmax(QK^T*scale)V ---
#define TQ 32
#define TK 64
__global__ __launch_bounds__(128) void k_flash(const u16* __restrict__ qB,
        const u16* __restrict__ kB, const u16* __restrict__ vT,
        float* __restrict__ seq) {
    __shared__ u16 lq[32][136];
    __shared__ u16 lk[64][136];
    __shared__ u16 lvT[128][72];
    __shared__ u16 lsP[32][72];
    int b = blockIdx.x, q0 = blockIdx.y * TQ, t = threadIdx.x;
    int w = t >> 6, lane = t & 63;
    int col = lane & 15, quad = lane >> 4;
    const float scale = 0.08838834764831845f;

    for (int p = 0; p < 4; ++p) {
        int idx = p * 128 + t;
        int r = idx >> 4, c8 = (idx & 15) * 8;
        *(uint4*)(&lq[r][c8]) = *(const uint4*)(qB + ((size_t)b * SEQ + q0 + r) * CDIM + c8);
    }
    f32x4 occ[8];
    f32x4 zero = {0.f, 0.f, 0.f, 0.f};
    #pragma unroll
    for (int ot = 0; ot < 8; ++ot) occ[ot] = zero;
    float rs_r[4] = {0.f, 0.f, 0.f, 0.f};

    for (int kc = 0; kc < SEQ / TK; ++kc) {
        __syncthreads();
        for (int p = 0; p < 8; ++p) {
            int idx = p * 128 + t;
            int r = idx >> 4, c8 = (idx & 15) * 8;
            *(uint4*)(&lk[r][c8]) =
                *(const uint4*)(kB + ((size_t)b * SEQ + kc * TK + r) * CDIM + c8);
        }
        for (int p = 0; p < 8; ++p) {
            int idx = p * 128 + t;
            int cc = idx >> 3, k8 = (idx & 7) * 8;
            *(uint4*)(&lvT[cc][k8]) =
                *(const uint4*)(vT + (size_t)b * CDIM * SEQ + (size_t)cc * SEQ + kc * TK + k8);
        }
        __syncthreads();
        // scores: 16 q-rows (this wave) x 64 keys
        f32x4 sacc[4];
        #pragma unroll
        for (int nt = 0; nt < 4; ++nt) sacc[nt] = zero;
        #pragma unroll
        for (int seg = 0; seg < 4; ++seg) {
            bf16x8 a = *(const bf16x8*)(&lq[w * 16 + col][seg * 32 + quad * 8]);
            #pragma unroll
            for (int nt = 0; nt < 4; ++nt) {
                bf16x8 bb = *(const bf16x8*)(&lk[nt * 16 + col][seg * 32 + quad * 8]);
                sacc[nt] = __builtin_amdgcn_mfma_f32_16x16x32_bf16(a, bb, sacc[nt], 0, 0, 0);
            }
        }
        // fixed-max softmax numerator: p = exp(s*scale); accumulate row-sums
        #pragma unroll
        for (int nt = 0; nt < 4; ++nt) {
            #pragma unroll
            for (int r = 0; r < 4; ++r) {
                float pv = __expf(sacc[nt][r] * scale);
                rs_r[r] += pv;
                lsP[w * 16 + quad * 4 + r][nt * 16 + col] = f2b(pv);
            }
        }
        // PV: contraction over 64 keys = 2 segs
        #pragma unroll
        for (int seg = 0; seg < 2; ++seg) {
            bf16x8 a = *(const bf16x8*)(&lsP[w * 16 + col][seg * 32 + quad * 8]);
            #pragma unroll
            for (int ot = 0; ot < 8; ++ot) {
                bf16x8 bb = *(const bf16x8*)(&lvT[ot * 16 + col][seg * 32 + quad * 8]);
                occ[ot] = __builtin_amdgcn_mfma_f32_16x16x32_bf16(a, bb, occ[ot], 0, 0, 0);
            }
        }
    }
    // row-sum reduce across the 16 lanes holding each row, then epilogue
    #pragma unroll
    for (int r = 0; r < 4; ++r) {
        #pragma unroll
        for (int msk = 1; msk < 16; msk <<= 1) rs_r[r] += __shfl_xor(rs_r[r], msk);
    }
    #pragma unroll
    for (int r = 0; r < 4; ++r) {
        float inv = 1.f / rs_r[r];
        int qi = q0 + w * 16 + quad * 4 + r;
        #pragma unroll
        for (int ot = 0; ot < 8; ++ot) {
            int cc = ot * 16 + col;
            size_t adr = ((size_t)b * SEQ + qi) * CDIM + cc;
            seq[adr] += occ[ot][r] * inv;
        }
    }
}

// ---------------- dense MoE + gated combine: seq fp32 -> comb fp32 ----------
__global__ __launch_bounds__(256) void k_moe(const float* __restrict__ seq,
        const float* __restrict__ ew1, const float* __restrict__ eb1,
        const float* __restrict__ ew2, const float* __restrict__ eb2,
        const float* __restrict__ gw, const float* __restrict__ gb,
        float* __restrict__ comb) {
    __shared__ float lseq[32][132];
    __shared__ float lh1[32][132];
    __shared__ u16 lwT[128][140];
    __shared__ float lgate[32][4];
    int b = blockIdx.x, s0 = blockIdx.y * 32, t = threadIdx.x;
    for (int p = 0; p < 4; ++p) {
        int idx = p * 256 + t;
        int r = idx >> 5, c4 = (idx & 31) * 4;
        *(float4*)(&lseq[r][c4]) = *(const float4*)(seq + ((size_t)b * SEQ + s0 + r) * CDIM + c4);
    }
    __syncthreads();
    if (t < 96) {
        int s = t & 31, e = t / 32;
        float acc = gb[e];
        for (int i = 0; i < CDIM; ++i) acc += lseq[s][i] * gw[i * 3 + e];
        lgate[s][e] = acc;
    }
    __syncthreads();
    if (t < 32) {
        float a0 = lgate[t][0], a1 = lgate[t][1], a2 = lgate[t][2];
        float mx = fmaxf(a0, fmaxf(a1, a2));
        float e0 = __expf(a0 - mx), e1 = __expf(a1 - mx), e2 = __expf(a2 - mx);
        float inv = 1.f / (e0 + e1 + e2);
        lgate[t][0] = e0 * inv; lgate[t][1] = e1 * inv; lgate[t][2] = e2 * inv;
    }
    int oc = t & 127, sg = t >> 7;
    float macc[16];
    #pragma unroll
    for (int j = 0; j < 16; ++j) macc[j] = 0.f;
    for (int e = 0; e < NEXP; ++e) {
        __syncthreads();
        for (int p = 0; p < 8; ++p) {
            int idx = p * 256 + t;
            int i = idx >> 4, oc8 = (idx & 15) * 8;
            const float* wp = ew1 + (size_t)e * CDIM * CDIM + i * CDIM + oc8;
            float4 u0 = *(const float4*)(wp);
            float4 u1 = *(const float4*)(wp + 4);
            lwT[oc8 + 0][i] = f2b(u0.x); lwT[oc8 + 1][i] = f2b(u0.y);
            lwT[oc8 + 2][i] = f2b(u0.z); lwT[oc8 + 3][i] = f2b(u0.w);
            lwT[oc8 + 4][i] = f2b(u1.x); lwT[oc8 + 5][i] = f2b(u1.y);
            lwT[oc8 + 6][i] = f2b(u1.z); lwT[oc8 + 7][i] = f2b(u1.w);
        }
        __syncthreads();
        {
            float acc[16];
            float bv = eb1[e * CDIM + oc];
            #pragma unroll
            for (int j = 0; j < 16; ++j) acc[j] = bv;
            for (int i = 0; i < CDIM; i += 4) {
                float wf[4]; ld4bf(&lwT[oc][i], wf);
                #pragma unroll
                for (int j = 0; j < 16; ++j) {
                    float4 sv = *(const float4*)(&lseq[sg * 16 + j][i]);
                    acc[j] += sv.x * wf[0] + sv.y * wf[1] + sv.z * wf[2] + sv.w * wf[3];
                }
            }
            #pragma unroll
            for (int j = 0; j < 16; ++j) lh1[sg * 16 + j][oc] = fmaxf(acc[j], 0.f);
        }
        __syncthreads();
        for (int p = 0; p < 8; ++p) {
            int idx = p * 256 + t;
            int i = idx >> 4, oc8 = (idx & 15) * 8;
            const float* wp = ew2 + (size_t)e * CDIM * CDIM + i * CDIM + oc8;
            float4 u0 = *(const float4*)(wp);
            float4 u1 = *(const float4*)(wp + 4);
            lwT[oc8 + 0][i] = f2b(u0.x); lwT[oc8 + 1][i] = f2b(u0.y);
            lwT[oc8 + 2][i] = f2b(u0.z); lwT[oc8 + 3][i] = f2b(u0.w);
            lwT[oc8 + 4][i] = f2b(u1.x); lwT[oc8 + 5][i] = f2b(u1.y);
            lwT[oc8 + 6][i] = f2b(u1.z); lwT[oc8 + 7][i] = f2b(u1.w);
        }
        __syncthreads();
        {
            float bv = eb2[e * CDIM + oc];
            float acc[16];
            #pragma unroll
            for (int j = 0; j < 16; ++j) acc[j] = bv;
            for (int i = 0; i < CDIM; i += 4) {
                float wf[4]; ld4bf(&lwT[oc][i], wf);
                #pragma unroll
                for (int j = 0; j < 16; ++j) {
                    float4 hv = *(const float4*)(&lh1[sg * 16 + j][i]);
                    acc[j] += hv.x * wf[0] + hv.y * wf[1] + hv.z * wf[2] + hv.w * wf[3];
                }
            }
            #pragma unroll
            for (int j = 0; j < 16; ++j) macc[j] += lgate[sg * 16 + j][e] * acc[j];
        }
    }
    #pragma unroll
    for (int j = 0; j < 16; ++j) {
        int s = sg * 16 + j;
        float mo = macc[j];
        float g = 1.f / (1.f + __expf(-mo));
        comb[((size_t)b * SEQ + s0 + s) * CDIM + oc] = g * mo + (1.f - g) * lseq[s][oc];
    }
}

// ---------------- hypernet layer 1: hh[b][j] = relu(cond@hw1 + hb1) ---------
__global__ __launch_bounds__(256) void k_h1(const float* __restrict__ cond,
        const float* __restrict__ hw1, const float* __restrict__ hb1,
        float* __restrict__ hh) {
    __shared__ float lcond[8][128];
    int t = threadIdx.x;
    int j = blockIdx.x * 256 + t;
    for (int r = 0; r < 4; ++r) {
        int e = r * 256 + t;
        lcond[e >> 7][e & 127] = cond[e];
    }
    __syncthreads();
    float acc[8];
    float bv = hb1[j];
    #pragma unroll
    for (int bb = 0; bb < 8; ++bb) acc[bb] = bv;
    for (int i = 0; i < CDIM; ++i) {
        float w = hw1[(size_t)i * HHID + j];
        #pragma unroll
        for (int bb = 0; bb < 8; ++bb) acc[bb] += lcond[bb][i] * w;
    }
    #pragma unroll
    for (int bb = 0; bb < 8; ++bb) hh[(size_t)bb * HHID + j] = fmaxf(acc[bb], 0.f);
}

// ---------------- hypernet layer 2 init: wk = hb2 --------------------------
__global__ __launch_bounds__(256) void k_h2init(const float* __restrict__ hb2,
                                                float* __restrict__ wkp) {
    int idx = blockIdx.x * 256 + threadIdx.x;
    wkp[idx] = hb2[idx & (NPAR - 1)];
}

// ---------------- hypernet layer 2: split-K streaming matmul (512 MB read) --
__global__ __launch_bounds__(256) void k_h2(const float* __restrict__ hh,
        const float* __restrict__ hw2, float* __restrict__ wkp) {
    __shared__ float lh[8][256];
    int t = threadIdx.x;
    int n0 = blockIdx.x * 1024 + t * 4;
    int k0 = blockIdx.y * 256;
    for (int p = 0; p < 8; ++p) {
        int idx = p * 256 + t;          // 2048 = 8*256
        int bb = idx >> 8, k = idx & 255;
        lh[bb][k] = hh[(size_t)bb * HHID + k0 + k];
    }
    __syncthreads();
    f32x4 acc[8];
    f32x4 zero = {0.f, 0.f, 0.f, 0.f};
    #pragma unroll
    for (int bb = 0; bb < 8; ++bb) acc[bb] = zero;
    for (int k = 0; k < 256; ++k) {
        f32x4 w = *(const f32x4*)(hw2 + (size_t)(k0 + k) * NPAR + n0);
        #pragma unroll
        for (int bb = 0; bb < 8; ++bb) acc[bb] += w * lh[bb][k];
    }
    #pragma unroll
    for (int bb = 0; bb < 8; ++bb) {
        #pragma unroll
        for (int j = 0; j < 4; ++j)
            atomicAdd(&wkp[(size_t)bb * NPAR + n0 + j], acc[bb][j]);
    }
}

// ---------------- per-sample 1x1 conv + residual -> out fp32 [B][C][S] ------
__global__ __launch_bounds__(256) void k_conv(const float* __restrict__ comb,
        const float* __restrict__ wkp, float* __restrict__ out) {
    __shared__ float lc[32][132];
    int b = blockIdx.x, s0 = blockIdx.y * 32, t = threadIdx.x;
    for (int p = 0; p < 4; ++p) {
        int idx = p * 256 + t;
        int r = idx >> 5, c4 = (idx & 31) * 4;
        *(float4*)(&lc[r][c4]) = *(const float4*)(comb + ((size_t)b * SEQ + s0 + r) * CDIM + c4);
    }
    __syncthreads();
    int s = t & 31, og = t >> 5;
    #pragma unroll
    for (int j = 0; j < 16; ++j) {
        int oc = og * 16 + j;
        const float* wrow = wkp + (size_t)b * NPAR + oc * CDIM;
        float acc = 0.f;
        for (int i = 0; i < CDIM; i += 4) {
            float4 wv = *(const float4*)(wrow + i);
            float4 cv = *(const float4*)(&lc[s][i]);
            acc += wv.x * cv.x + wv.y * cv.y + wv.z * cv.z + wv.w * cv.w;
        }
        out[(size_t)b * CDIM * SEQ + (size_t)oc * SEQ + s0 + s] = lc[s][oc] + acc;
    }
}

extern "C" void kernel_launch(void* const* d_in, const int* in_sizes, int n_in,
                              void* d_out, int out_size, void* d_ws, size_t ws_size,
                              hipStream_t stream) {
    (void)in_sizes; (void)n_in; (void)out_size; (void)ws_size;
    const float* feat = (const float*)d_in[0];
    const float* cond = (const float*)d_in[1];
    const float* qw = (const float*)d_in[2];
    const float* kw = (const float*)d_in[3];
    const float* vw = (const float*)d_in[4];
    const float* qb = (const float*)d_in[5];
    const float* kb = (const float*)d_in[6];
    const float* vb = (const float*)d_in[7];
    const float* ew1 = (const float*)d_in[8];
    const float* eb1 = (const float*)d_in[9];
    const float* ew2 = (const float*)d_in[10];
    const float* eb2 = (const float*)d_in[11];
    const float* gw = (const float*)d_in[12];
    const float* gb = (const float*)d_in[13];
    const float* hw1 = (const float*)d_in[14];
    const float* hb1 = (const float*)d_in[15];
    const float* hw2 = (const float*)d_in[16];
    const float* hb2 = (const float*)d_in[17];
    float* out = (float*)d_out;

    char* ws = (char*)d_ws;
    float* seq  = (float*)(ws);                     // 9,437,184 B
    float* comb = (float*)(ws + 9437184);           // 9,437,184 B
    u16* qBuf   = (u16*)(ws + 18874368);            // 4,718,592 B
    u16* kBuf   = (u16*)(ws + 23592960);            // 4,718,592 B
    u16* vTbuf  = (u16*)(ws + 28311552);            // 4,718,592 B
    float* hh   = (float*)(ws + 33030144);          //   262,144 B
    float* wkp  = (float*)(ws + 33292288);          //   524,288 B  (total 33.8 MB)

    k_transpose<<<dim3(8, 36), 256, 0, stream>>>(feat, seq);
    for (int l = 0; l < 2; ++l) {
        k_qkv<<<dim3(8, 72), 256, 0, stream>>>(seq,
                qw + l * CDIM * CDIM, kw + l * CDIM * CDIM, vw + l * CDIM * CDIM,
                qb + l * CDIM, kb + l * CDIM, vb + l * CDIM,
                qBuf, kBuf, vTbuf);
        k_flash<<<dim3(8, 72), 128, 0, stream>>>(qBuf, kBuf, vTbuf, seq);
    }
    k_moe<<<dim3(8, 72), 256, 0, stream>>>(seq, ew1, eb1, ew2, eb2, gw, gb, comb);
    k_h1<<<dim3(32), 256, 0, stream>>>(cond, hw1, hb1, hh);
    k_h2init<<<dim3(512), 256, 0, stream>>>(hb2, wkp);
    k_h2<<<dim3(16, 32), 256, 0, stream>>>(hh, hw2, wkp);
    k_conv<<<dim3(8, 72), 256, 0, stream>>>(comb, wkp, out);
}